// Round 8
// baseline (207.158 us; speedup 1.0000x reference)
//
#include <hip/hip_runtime.h>
#include <hip/hip_bf16.h>

#define NBLK 100
#define DIM 128
#define EVEC (NBLK * DIM)          // 12800 floats per accumulator array
#define SLICE (2 * EVEC + NBLK)    // 25700 floats per slice
#define EPSV 1e-8f
#define G_WGS 256                  // 1 WG per CU
#define SCLAMP 6.0f
#define SSCALE16 64.0f             // 2^6 fixed point for sums (R6-proven)
#define INV_SSCALE16 (1.0f / 64.0f)
#define SBIAS 384                  // per-add bias; half <= 768/add
#define NSCALE 262144.0f           // 2^18 fixed point for unit sums (int32)
#define INV_NSCALE (1.0f / NSCALE)
// Overflow: adds per (WG,block) ~ Poisson(1e6/(256*100)=39); 16-bit half
// overflows at >=86 adds: Chernoff P ~ 1.7e-9 x 25600 cells ~ 4e-5. Safe.
// nsum int32: 39 x 2^18 << 2^31.

// sum over 16 lanes via DPP (pure VALU; verified R4-R7)
__device__ __forceinline__ float dpp_qsum16(float x) {
  int xi, yi;
  xi = __builtin_bit_cast(int, x);
  yi = __builtin_amdgcn_update_dpp(0, xi, 0xB1, 0xF, 0xF, false); // quad_perm(1,0,3,2)
  x += __builtin_bit_cast(float, yi);
  xi = __builtin_bit_cast(int, x);
  yi = __builtin_amdgcn_update_dpp(0, xi, 0x4E, 0xF, 0xF, false); // quad_perm(2,3,0,1)
  x += __builtin_bit_cast(float, yi);
  xi = __builtin_bit_cast(int, x);
  yi = __builtin_amdgcn_update_dpp(0, xi, 0x124, 0xF, 0xF, false); // row_ror:4
  x += __builtin_bit_cast(float, yi);
  xi = __builtin_bit_cast(int, x);
  yi = __builtin_amdgcn_update_dpp(0, xi, 0x128, 0xF, 0xF, false); // row_ror:8
  x += __builtin_bit_cast(float, yi);
  return x;
}

// ---------------------------------------------------------------------------
// Kernel 1: ONE POINT PER WAVE. Lane l loads float2 = dims (2l, 2l+1): one
// dwordx2 per point (512 B/wave/instr, 8 B/lane). 64-lane norm reduce =
// 4 DPP + 2 shfl. Exactly 3 bank-free LDS atomics per point (u32-packed
// 16-bit sums + 2x int32 nsums), 1-cell cnt atomic on lane 0. 3-deep
// rotating register prefetch (~6 loads in flight, counted vmcnt waits),
// no barriers in the loop -- the closest possible analog of the reference
// streaming-reduction structure (RMSNorm/LN at 82-86% of HBM).
// ---------------------------------------------------------------------------
__global__ __launch_bounds__(1024) void rbc_accum(
    const float2* __restrict__ zf2, const int* __restrict__ ids,
    float* __restrict__ ws, int N, int nwaves) {
  __shared__ unsigned lsum16[NBLK * 64];  // 25.6 KB; cell l: dims (2l | 2l+1<<16)
  __shared__ int lnsum[NBLK * DIM];       // 51.2 KB; cell l -> dim 2l, cell l+64 -> dim 2l+1
  __shared__ int lcnt[NBLK];              // 0.4 KB
  const int tid = threadIdx.x;
  for (int e = tid; e < NBLK * 64; e += 1024) lsum16[e] = 0u;
  for (int e = tid; e < EVEC; e += 1024) lnsum[e] = 0;
  if (tid < NBLK) lcnt[tid] = 0;
  __syncthreads();

  const int lane = tid & 63;
  const int gw = blockIdx.x * 16 + (tid >> 6);  // global wave id

#define RBC_BODY(V, BB)                                                       \
  {                                                                           \
    float sq = V.x * V.x + V.y * V.y;                                         \
    sq = dpp_qsum16(sq);                                                      \
    sq += __shfl_xor(sq, 16);                                                 \
    sq += __shfl_xor(sq, 32);                                                 \
    const float rn =                                                          \
        __builtin_amdgcn_rcpf(fmaxf(__builtin_amdgcn_sqrtf(sq), EPSV));       \
    const float rnN = rn * NSCALE;                                            \
    const int q0 = __float2int_rn(                                            \
        fminf(fmaxf(V.x, -SCLAMP), SCLAMP) * SSCALE16) + SBIAS;               \
    const int q1 = __float2int_rn(                                            \
        fminf(fmaxf(V.y, -SCLAMP), SCLAMP) * SSCALE16) + SBIAS;               \
    atomicAdd(&lsum16[BB * 64 + lane], (unsigned)(q0 | (q1 << 16)));          \
    atomicAdd(&lnsum[BB * DIM + lane], __float2int_rn(V.x * rnN));            \
    atomicAdd(&lnsum[BB * DIM + 64 + lane], __float2int_rn(V.y * rnN));       \
    if (lane == 0) atomicAdd(&lcnt[BB], 1);                                   \
  }

  // 3-deep rotating prefetch; all guards are wave-uniform
  int iA = gw, iB = gw + nwaves, iC = gw + 2 * nwaves;
  float2 vA = {}, vB = {}, vC = {};
  int bA = 0, bB = 0, bC = 0;
  if (iA < N) { vA = zf2[(size_t)iA * 64 + lane]; bA = ids[iA]; }
  if (iB < N) { vB = zf2[(size_t)iB * 64 + lane]; bB = ids[iB]; }
  if (iC < N) { vC = zf2[(size_t)iC * 64 + lane]; bC = ids[iC]; }
  while (iA < N) {
    const int iD = iC + nwaves;
    float2 vD = {};
    int bD = 0;
    if (iD < N) { vD = zf2[(size_t)iD * 64 + lane]; bD = ids[iD]; }
    RBC_BODY(vA, bA);
    iA = iB; vA = vB; bA = bB;
    iB = iC; vB = vC; bB = bC;
    iC = iD; vC = vD; bC = bD;
  }
#undef RBC_BODY
  __syncthreads();

  // flush to plain-layout float slice (no permutation anywhere)
  float* slice = ws + (size_t)blockIdx.x * SLICE;
  for (int e = tid; e < NBLK * 64; e += 1024) {
    const int b = e >> 6;
    const int l = e & 63;
    const unsigned vs = lsum16[e];
    const int cb = lcnt[b] * SBIAS;
    slice[b * DIM + 2 * l]     = (float)((int)(vs & 0xFFFFu) - cb) * INV_SSCALE16;
    slice[b * DIM + 2 * l + 1] = (float)((int)(vs >> 16) - cb) * INV_SSCALE16;
    slice[EVEC + b * DIM + 2 * l]     = (float)lnsum[b * DIM + l] * INV_NSCALE;
    slice[EVEC + b * DIM + 2 * l + 1] = (float)lnsum[b * DIM + 64 + l] * INV_NSCALE;
  }
  if (tid < NBLK) slice[2 * EVEC + tid] = (float)lcnt[tid];
}

// ---------------------------------------------------------------------------
// Kernel 2: one WG (1024 thr) per road block; 8-way split over G slices,
// emit {ND, S2, cnt}.
// ---------------------------------------------------------------------------
__global__ __launch_bounds__(1024) void rbc_blockstat(
    const float* __restrict__ ws, float* __restrict__ stat, int G) {
  __shared__ float sp[1024];
  __shared__ float np_[1024];
  const int b = blockIdx.x;
  const int t = threadIdx.x;
  const int d = t & 127;
  const int oct = t >> 7;
  const int gpo = (G + 7) >> 3;
  const int g0 = oct * gpo;
  const int g1 = (g0 + gpo < G) ? (g0 + gpo) : G;
  float s = 0.f, n = 0.f;
  for (int g = g0; g < g1; ++g) {
    const float* f = ws + (size_t)g * SLICE + (size_t)b * DIM;
    s += f[d];
    n += f[EVEC + d];
  }
  sp[t] = s;
  np_[t] = n;

  if (t >= 256 && t < 320) {
    const int l = t - 256;
    float c = 0.f;
    for (int g = l; g < G; g += 64) c += ws[(size_t)g * SLICE + 2 * EVEC + b];
#pragma unroll
    for (int m = 1; m < 64; m <<= 1) c += __shfl_xor(c, m);
    if (l == 0) stat[b * 4 + 2] = c;
  }
  __syncthreads();

  if (t < 128) {
    float ss = 0.f, nn = 0.f;
#pragma unroll
    for (int k = 0; k < 8; ++k) { ss += sp[t + 128 * k]; nn += np_[t + 128 * k]; }
    sp[t] = ss * ss;
    np_[t] = nn * ss;
  }
  __syncthreads();

  if (t < 64) {
    float S2 = sp[t] + sp[t + 64];
    float ND = np_[t] + np_[t + 64];
#pragma unroll
    for (int m = 1; m < 64; m <<= 1) {
      S2 += __shfl_xor(S2, m);
      ND += __shfl_xor(ND, m);
    }
    if (t == 0) {
      stat[b * 4 + 0] = ND;
      stat[b * 4 + 1] = S2;
    }
  }
}

// ---------------------------------------------------------------------------
// Kernel 3: 100 triples -> scalar.
// ---------------------------------------------------------------------------
__global__ __launch_bounds__(128) void rbc_final(const float* __restrict__ stat,
                                                 float* __restrict__ out) {
  __shared__ float lv[2];
  __shared__ float lc[2];
  const int t = threadIdx.x;
  float val = 0.f, vc = 0.f;
  if (t < NBLK) {
    const float ND = stat[t * 4 + 0];
    const float S2 = stat[t * 4 + 1];
    const float cnt = stat[t * 4 + 2];
    const float cnt1 = fmaxf(cnt, 1.0f);
    const float cn = fmaxf(sqrtf(S2) / cnt1, EPSV);
    const float mean_cos = ND / (cnt1 * cnt1 * cn);
    if (cnt > 1.0f) { val = 1.0f - mean_cos; vc = 1.0f; }
  }
#pragma unroll
  for (int m = 1; m < 64; m <<= 1) {
    val += __shfl_xor(val, m);
    vc += __shfl_xor(vc, m);
  }
  if ((t & 63) == 0) { lv[t >> 6] = val; lc[t >> 6] = vc; }
  __syncthreads();
  if (t == 0) out[0] = (lv[0] + lv[1]) / fmaxf(lc[0] + lc[1], 1.0f);
}

extern "C" void kernel_launch(void* const* d_in, const int* in_sizes, int n_in,
                              void* d_out, int out_size, void* d_ws, size_t ws_size,
                              hipStream_t stream) {
  const float* z = (const float*)d_in[0];
  const int* ids = (const int*)d_in[1];
  const int N = in_sizes[1];
  float* out = (float*)d_out;
  float* ws = (float*)d_ws;

  size_t cap = (ws_size - 400 * sizeof(float)) / (sizeof(float) * (size_t)SLICE);
  int G = G_WGS;
  if (cap < (size_t)G) G = (int)(cap > 1 ? cap : 1);
  const int nwaves = G * 16;

  rbc_accum<<<G, 1024, 0, stream>>>((const float2*)z, ids, ws, N, nwaves);

  float* stat = ws + (size_t)G * SLICE;
  rbc_blockstat<<<NBLK, 1024, 0, stream>>>(ws, stat, G);
  rbc_final<<<1, 128, 0, stream>>>(stat, out);
}

// Round 9
// 121.790 us; speedup vs baseline: 1.7009x; 1.7009x over previous
//
#include <hip/hip_runtime.h>
#include <hip/hip_bf16.h>

#define NBLK 100
#define DIM 128
#define EVEC (NBLK * DIM)          // 12800 elements per accumulator array
#define SLICE (2 * EVEC + NBLK)    // 25700 floats per slice
#define EPSV 1e-8f
#define SSCALE 4194304.0f          // 2^22 fixed-point scale for sums
#define NSCALE 16777216.0f         // 2^24 fixed-point scale for unit-vector sums
#define INV_SSCALE (1.0f / SSCALE)
#define INV_NSCALE (1.0f / NSCALE)

// 16-lane sum reduction via DPP (pure VALU; no ds_swizzle lgkmcnt stalls).
// quad_perm xor1, xor2 then row_ror:4, row_ror:8 (rows of 16 on CDNA).
__device__ __forceinline__ float dpp_qsum16(float x) {
  int xi, yi;
  xi = __builtin_bit_cast(int, x);
  yi = __builtin_amdgcn_update_dpp(0, xi, 0xB1, 0xF, 0xF, false); // quad_perm(1,0,3,2)
  x += __builtin_bit_cast(float, yi);
  xi = __builtin_bit_cast(int, x);
  yi = __builtin_amdgcn_update_dpp(0, xi, 0x4E, 0xF, 0xF, false); // quad_perm(2,3,0,1)
  x += __builtin_bit_cast(float, yi);
  xi = __builtin_bit_cast(int, x);
  yi = __builtin_amdgcn_update_dpp(0, xi, 0x124, 0xF, 0xF, false); // row_ror:4
  x += __builtin_bit_cast(float, yi);
  xi = __builtin_bit_cast(int, x);
  yi = __builtin_amdgcn_update_dpp(0, xi, 0x128, 0xF, 0xF, false); // row_ror:8
  x += __builtin_bit_cast(float, yi);
  return x;
}

// ---------------------------------------------------------------------------
// Kernel 1 (best-measured variant, R4: 122.09 us): one pass over z. 16 lanes
// per point (2x float4), 4 points per wave group, int32 fixed-point LDS
// atomics (native ds_add_u32; float LDS atomics compile to CAS loops -> R1's
// 11x slowdown). 1-deep register double-buffer over two interleaved group
// streams. Norm reduce via DPP; rcp/sqrt builtins. Bank-spread dim
// permutation, identical for sums and nsums -> downstream dots/norms
// invariant (verified absmax 0.0 across R2-R8).
// Structural note: 8 variants (R2-R8) converge at ~4.8 TB/s delivered read
// for this stream+scatter pattern; this is the fastest measured form.
// ---------------------------------------------------------------------------
__global__ __launch_bounds__(1024) void rbc_accum(
    const float4* __restrict__ z4, const int* __restrict__ ids,
    float* __restrict__ ws, int N, int nwaves) {
  __shared__ int lsum[EVEC];
  __shared__ int lnsum[EVEC];
  __shared__ int lcnt[NBLK];
  const int tid = threadIdx.x;
  for (int e = tid; e < EVEC; e += 1024) { lsum[e] = 0; lnsum[e] = 0; }
  if (tid < NBLK) lcnt[tid] = 0;
  __syncthreads();

  const int lane = tid & 63;
  const int q  = lane >> 4;   // quarter (which of 4 points in a group)
  const int r  = lane & 15;   // lane within quarter
  const int qp = q & 1;       // quarter parity for bank spreading
  const int w = blockIdx.x * (blockDim.x >> 6) + (tid >> 6);
  const int ngroups = N >> 2;

#define RBC_POINT_BODY(A0, A1, BB)                                           \
  {                                                                          \
    float sq = A0.x * A0.x + A0.y * A0.y + A0.z * A0.z + A0.w * A0.w +       \
               A1.x * A1.x + A1.y * A1.y + A1.z * A1.z + A1.w * A1.w;        \
    sq = dpp_qsum16(sq);                                                     \
    const float rn =                                                         \
        __builtin_amdgcn_rcpf(fmaxf(__builtin_amdgcn_sqrtf(sq), EPSV));      \
    const float rnN = rn * NSCALE;                                           \
    const float v0[4] = {A0.x, A0.y, A0.z, A0.w};                            \
    const float v1[4] = {A1.x, A1.y, A1.z, A1.w};                            \
    const int base = BB * DIM;                                               \
    _Pragma("unroll")                                                        \
    for (int s = 0; s < 4; ++s) {                                            \
      const float x0 = qp ? v0[s ^ 1] : v0[s];                               \
      const float x1 = qp ? v1[s ^ 1] : v1[s];                               \
      const int p0 = base + r + ((((s & 1) ^ qp)) << 4) + ((s >> 1) << 5);   \
      atomicAdd(&lsum[p0], __float2int_rn(x0 * SSCALE));                     \
      atomicAdd(&lnsum[p0], __float2int_rn(x0 * rnN));                       \
      atomicAdd(&lsum[p0 + 64], __float2int_rn(x1 * SSCALE));                \
      atomicAdd(&lnsum[p0 + 64], __float2int_rn(x1 * rnN));                  \
    }                                                                        \
    if (r == 0) atomicAdd(&lcnt[BB], 1);                                     \
  }

  // two interleaved group streams (j0, j1), double-buffered one step ahead
  const int stride2 = nwaves << 1;
  int j0 = w, j1 = w + nwaves;
  bool h0 = j0 < ngroups, h1 = j1 < ngroups;
  float4 A0, A1, B0, B1;
  int bA = 0, bB = 0;
  if (h0) {
    const int i = (j0 << 2) + q;
    const float4* p = z4 + ((size_t)i << 5);
    A0 = p[r]; A1 = p[r + 16]; bA = ids[i];
  }
  if (h1) {
    const int i = (j1 << 2) + q;
    const float4* p = z4 + ((size_t)i << 5);
    B0 = p[r]; B1 = p[r + 16]; bB = ids[i];
  }
  while (h0) {
    const int n0 = j0 + stride2, n1 = j1 + stride2;
    const bool hn0 = n0 < ngroups, hn1 = n1 < ngroups;
    float4 NA0, NA1, NB0, NB1;
    int nbA = 0, nbB = 0;
    if (hn0) {  // issue next loads BEFORE processing current
      const int i = (n0 << 2) + q;
      const float4* p = z4 + ((size_t)i << 5);
      NA0 = p[r]; NA1 = p[r + 16]; nbA = ids[i];
    }
    if (hn1) {
      const int i = (n1 << 2) + q;
      const float4* p = z4 + ((size_t)i << 5);
      NB0 = p[r]; NB1 = p[r + 16]; nbB = ids[i];
    }
    RBC_POINT_BODY(A0, A1, bA);
    if (h1) RBC_POINT_BODY(B0, B1, bB);
    A0 = NA0; A1 = NA1; B0 = NB0; B1 = NB1; bA = nbA; bB = nbB;
    j0 = n0; j1 = n1; h0 = hn0; h1 = hn1;
  }
  // tail points (N not multiple of 4): block 0, wave 0
  if (blockIdx.x == 0 && (tid >> 6) == 0 && (N & 3)) {
    const int i = ((ngroups << 2)) + q;
    if (q < (N & 3)) {
      const float4* zp = z4 + ((size_t)i << 5);
      const float4 a0 = zp[r];
      const float4 a1 = zp[r + 16];
      const int b = ids[i];
      RBC_POINT_BODY(a0, a1, b);
    }
  }
#undef RBC_POINT_BODY
  __syncthreads();

  float* slice = ws + (size_t)blockIdx.x * SLICE;
  for (int e = tid; e < EVEC; e += 1024) {
    slice[e] = (float)lsum[e] * INV_SSCALE;
    slice[EVEC + e] = (float)lnsum[e] * INV_NSCALE;
  }
  if (tid < NBLK) slice[2 * EVEC + tid] = (float)lcnt[tid];
}

// ---------------------------------------------------------------------------
// Kernel 2: one WG per road block; reduce across G slices, emit {ND,S2,cnt}.
// ---------------------------------------------------------------------------
__global__ __launch_bounds__(512) void rbc_blockstat(
    const float* __restrict__ ws, float* __restrict__ stat, int G) {
  __shared__ float sp[512];
  __shared__ float np_[512];
  const int b = blockIdx.x;
  const int t = threadIdx.x;
  const int d = t & 127;
  const int qq = t >> 7;
  const int gpq = (G + 3) >> 2;
  const int g0 = qq * gpq;
  const int g1 = (g0 + gpq < G) ? (g0 + gpq) : G;
  float s = 0.f, n = 0.f;
  for (int g = g0; g < g1; ++g) {
    const float* f = ws + (size_t)g * SLICE + (size_t)b * DIM;
    s += f[d];
    n += f[EVEC + d];
  }
  sp[t] = s;
  np_[t] = n;

  if (t >= 256 && t < 320) {
    const int l = t - 256;
    float c = 0.f;
    for (int g = l; g < G; g += 64) c += ws[(size_t)g * SLICE + 2 * EVEC + b];
#pragma unroll
    for (int m = 1; m < 64; m <<= 1) c += __shfl_xor(c, m);
    if (l == 0) stat[b * 4 + 2] = c;
  }
  __syncthreads();

  if (t < 128) {
    const float ss = sp[t] + sp[t + 128] + sp[t + 256] + sp[t + 384];
    const float nn = np_[t] + np_[t + 128] + np_[t + 256] + np_[t + 384];
    sp[t] = ss * ss;
    np_[t] = nn * ss;
  }
  __syncthreads();

  if (t < 64) {
    float S2 = sp[t] + sp[t + 64];
    float ND = np_[t] + np_[t + 64];
#pragma unroll
    for (int m = 1; m < 64; m <<= 1) {
      S2 += __shfl_xor(S2, m);
      ND += __shfl_xor(ND, m);
    }
    if (t == 0) {
      stat[b * 4 + 0] = ND;
      stat[b * 4 + 1] = S2;
    }
  }
}

// ---------------------------------------------------------------------------
// Kernel 3: 100 triples -> scalar.
// ---------------------------------------------------------------------------
__global__ __launch_bounds__(128) void rbc_final(const float* __restrict__ stat,
                                                 float* __restrict__ out) {
  __shared__ float lv[2];
  __shared__ float lc[2];
  const int t = threadIdx.x;
  float val = 0.f, vc = 0.f;
  if (t < NBLK) {
    const float ND = stat[t * 4 + 0];
    const float S2 = stat[t * 4 + 1];
    const float cnt = stat[t * 4 + 2];
    const float cnt1 = fmaxf(cnt, 1.0f);
    const float cn = fmaxf(sqrtf(S2) / cnt1, EPSV);
    const float mean_cos = ND / (cnt1 * cnt1 * cn);
    if (cnt > 1.0f) { val = 1.0f - mean_cos; vc = 1.0f; }
  }
#pragma unroll
  for (int m = 1; m < 64; m <<= 1) {
    val += __shfl_xor(val, m);
    vc += __shfl_xor(vc, m);
  }
  if ((t & 63) == 0) { lv[t >> 6] = val; lc[t >> 6] = vc; }
  __syncthreads();
  if (t == 0) out[0] = (lv[0] + lv[1]) / fmaxf(lc[0] + lc[1], 1.0f);
}

extern "C" void kernel_launch(void* const* d_in, const int* in_sizes, int n_in,
                              void* d_out, int out_size, void* d_ws, size_t ws_size,
                              hipStream_t stream) {
  const float* z = (const float*)d_in[0];
  const int* ids = (const int*)d_in[1];
  const int N = in_sizes[1];
  float* out = (float*)d_out;
  float* ws = (float*)d_ws;

  size_t cap = (ws_size - 400 * sizeof(float)) / (sizeof(float) * (size_t)SLICE);
  int G = 256;
  if (cap < (size_t)G) G = (int)(cap > 1 ? cap : 1);
  const int nwaves = G * (1024 / 64);

  rbc_accum<<<G, 1024, 0, stream>>>((const float4*)z, ids, ws, N, nwaves);

  float* stat = ws + (size_t)G * SLICE;
  rbc_blockstat<<<NBLK, 512, 0, stream>>>(ws, stat, G);
  rbc_final<<<1, 128, 0, stream>>>(stat, out);
}